// Round 16
// baseline (25.265 us; speedup 1.0000x reference)
//
#include <hip/hip_runtime.h>
#include <math.h>

#define NB 2
#define NP 1200
#define NF 1000
#define IH 128
#define IW 128
#define TH 512
#define TW 512

#define TX 16
#define TY 16
#define NTILE (TX*TY)          // 256 tiles per batch
#define NPIX (NB*IH*IW)        // 32768
#define NSLOT 16               // wave-slots per tile; each owns 64 contiguous faces

// 48-byte record: [c0..c3][c4..c7][c8,z0,z1,z2]
struct __align__(16) FaceG { float4 A, B, C; };

// ws layout
#define FG_OFF   0
#define FG_BYTES (NB*NF*48)
#define BB_OFF   ((FG_BYTES + 255) & ~255)
#define BB_BYTES (NB*NF*16)
#define ZK_OFF   ((BB_OFF + BB_BYTES + 255) & ~255)
#define ZK_BYTES (NPIX*8)
#define MK_OFF   (ZK_OFF + ZK_BYTES)

// monotone float <-> uint maps (ascending order preserved)
__device__ __forceinline__ unsigned int fmap(float f) {
    unsigned int u = __float_as_uint(f);
    return (u & 0x80000000u) ? ~u : (u | 0x80000000u);
}
__device__ __forceinline__ float funmap(unsigned int u) {
    return __uint_as_float((u & 0x80000000u) ? (u & 0x7fffffffu) : ~u);
}

__global__ __launch_bounds__(256) void prep_kernel(
        const float* __restrict__ points,
        const int*  __restrict__ faces,
        const float* __restrict__ rot,
        const float* __restrict__ cpos,
        const float* __restrict__ proj,
        float* __restrict__ normal_out,
        FaceG* __restrict__ fg,
        float4* __restrict__ bbox,
        unsigned long long* __restrict__ zkey,
        unsigned int* __restrict__ mkey)
{
#pragma clang fp contract(off)
    int t = blockIdx.x * 256 + threadIdx.x;       // 0..32767
    if (t < NPIX) { zkey[t] = ~0ull; mkey[t] = 0u; }
    if (t >= NB * NF) return;
    int b = t / NF;
    int f = t - b * NF;
    const float* R = rot + b * 9;
    float ccx = cpos[b*3+0], ccy = cpos[b*3+1], ccz = cpos[b*3+2];
    float pr0 = proj[0], pr1 = proj[1], pr2 = proj[2];

    float qx[3], qy[3], qz[3], sx[3], sy[3];
    for (int k = 0; k < 3; ++k) {
        int vi = faces[f*3 + k];
        const float* P = points + (b*NP + vi) * 3;
        float vx = P[0] - ccx, vy = P[1] - ccy, vz = P[2] - ccz;
        float q0 = (vx*R[0] + vy*R[1]) + vz*R[2];
        float q1 = (vx*R[3] + vy*R[4]) + vz*R[5];
        float q2 = (vx*R[6] + vy*R[7]) + vz*R[8];
        qx[k] = q0; qy[k] = q1; qz[k] = q2;
        sx[k] = (q0*pr0) / (q2*pr2);   // IEEE divide, reference order
        sy[k] = (q1*pr1) / (q2*pr2);
    }
    float x0 = sx[0], y0 = sy[0];
    float x1 = sx[1], y1 = sy[1];
    float x2 = sx[2], y2 = sy[2];

    FaceG rec;
    rec.A = make_float4(y1 - y2, x2 - x1, x1*y2 - x2*y1, y2 - y0);
    rec.B = make_float4(x0 - x2, x2*y0 - x0*y2, y0 - y1, x1 - x0);
    rec.C = make_float4(x0*y1 - x1*y0, qz[0], qz[1], qz[2]);
    fg[t] = rec;

    float e1x = qx[1]-qx[0], e1y = qy[1]-qy[0], e1z = qz[1]-qz[0];
    float e2x = qx[2]-qx[0], e2y = qy[2]-qy[0], e2z = qz[2]-qz[0];
    float nx = e1y*e2z - e1z*e2y;
    float ny = e1z*e2x - e1x*e2z;
    float nz = e1x*e2y - e1y*e2x;
    bool front = nz > 0.0f;
    float nlen = sqrtf(((nx*nx + ny*ny) + nz*nz) + 1e-8f);
    float nd = nlen + 1e-15f;
    normal_out[t*3+0] = nx / nd;
    normal_out[t*3+1] = ny / nd;
    normal_out[t*3+2] = nz / nd;

    // conservative pixel-space bbox (xmin, ymin, xmax, ymax)
    float4 bb;
    if (!front) {
        bb = make_float4(1e9f, 1e9f, -1e9f, -1e9f);          // empty
    } else {
        float A2 = (x1-x0)*(y2-y0) - (x2-x0)*(y1-y0);
        if (fabsf(A2) < 1e-6f) {
            bb = make_float4(-1e9f, -1e9f, 1e9f, 1e9f);      // degenerate: everywhere
        } else {
            // {min bary >= -delta} == triangle scaled by (1+3*delta) about centroid;
            // delta = 0.15 -> culled faces contribute <= sigmoid(-7.5) ~ 5.5e-4.
            const float s = 1.45f;
            float cx = (x0 + x1 + x2) * (1.0f/3.0f);
            float cy = (y0 + y1 + y2) * (1.0f/3.0f);
            float xa = cx + s*(x0-cx), xb = cx + s*(x1-cx), xc = cx + s*(x2-cx);
            float ya = cy + s*(y0-cy), yb = cy + s*(y1-cy), yc = cy + s*(y2-cy);
            float xmin = fminf(fminf(xa,xb),xc), xmax = fmaxf(fmaxf(xa,xb),xc);
            float ymin = fminf(fminf(ya,yb),yc), ymax = fmaxf(fmaxf(ya,yb),yc);
            bb.x = (xmin + 1.0f) * (IW*0.5f) - 0.5f - 1.0f;  // pxmin
            bb.z = (xmax + 1.0f) * (IW*0.5f) - 0.5f + 1.0f;  // pxmax
            bb.y = (1.0f - ymax) * (IH*0.5f) - 0.5f - 1.0f;  // pymin
            bb.w = (1.0f - ymin) * (IH*0.5f) - 0.5f + 1.0f;  // pymax
        }
    }
    bbox[t] = bb;
}

#define EVALF(F_, fidx_) do {                                              \
    float w0 = ((F_).A.x*px + (F_).A.y*py) + (F_).A.z;                     \
    float w1 = ((F_).A.w*px + (F_).B.x*py) + (F_).B.y;                     \
    float w2 = ((F_).B.z*px + (F_).B.w*py) + (F_).C.x;                     \
    float den = (w0 + w1) + w2;                                            \
    den = den + ((den >= 0.0f) ? 1e-8f : -1e-8f);                          \
    bool sp = den > 0.0f;                                                  \
    float mn = fminf(fminf(w0, w1), w2);                                   \
    float mx = fmaxf(fmaxf(w0, w1), w2);                                   \
    float wsel = sp ? mn : mx;                                             \
    float dmin = wsel * __builtin_amdgcn_rcpf(den);                        \
    lm = max(lm, fmap(dmin));                                              \
    bool inside = sp ? (mn >= 0.0f) : (mx <= 0.0f);                        \
    if (inside) {                                                          \
        float b0 = w0 / den, b1 = w1 / den, b2 = w2 / den;                 \
        float z = (b0*(F_).C.y + b1*(F_).C.z) + b2*(F_).C.w;               \
        unsigned long long key =                                           \
            ((unsigned long long)fmap(z) << 32) | (unsigned int)(fidx_);   \
        lz = lz < key ? lz : key;                                          \
    }                                                                      \
} while (0)

// 2048 blocks x 4 waves = 8192 waves = 512 tiles x 16 slots.
// Wave (tile, slot) owns contiguous faces [slot*64, slot*64+64).
// Full-wave cull: lane l tests bbox[base+l] (all 64 lanes useful, one
// coalesced round), 64-bit ballot -> survivor mask; cold waves exit fast.
__global__ __launch_bounds__(256) void raster_kernel(
        const FaceG* __restrict__ fg,
        const float4* __restrict__ bbox,
        unsigned long long* __restrict__ zkey,
        unsigned int* __restrict__ mkey)
{
#pragma clang fp contract(off)
    unsigned int vid = (blockIdx.x * 1337u) & 2047u;   // bijective scramble
    int bt   = vid >> 2;                // 0..511 = batch*256 + tile
    int sgrp = vid & 3;                 // slot group 0..3
    int b    = bt >> 8;
    int tile = bt & (NTILE - 1);
    int wib  = threadIdx.x >> 6;
    int l    = threadIdx.x & 63;
    int slot = sgrp * 4 + wib;          // 0..15
    int base = slot * 64;               // first face of this wave's span

    int tx = tile & (TX - 1), ty = tile >> 4;
    float txlo = (float)(tx << 3), txhi = (float)((tx << 3) + 7);
    float tylo = (float)(ty << 3), tyhi = (float)((ty << 3) + 7);

    // ---- full-wave cull: one coalesced bbox load per lane ----
    const float4* bbb = bbox + b * NF;
    int fi = base + l;
    bool valid = fi < NF;
    float4 bb = bbb[valid ? fi : (NF - 1)];
    bool keep = valid & (bb.x <= txhi) & (bb.z >= txlo)
                      & (bb.y <= tyhi) & (bb.w >= tylo);
    unsigned long long mask = __ballot(keep);
    if (mask == 0ull) return;           // cold wave: done after one round-trip

    int px_i = (tx << 3) | (l & 7);
    int py_i = (ty << 3) | (l >> 3);
    float px = (px_i + 0.5f) / (float)IW * 2.0f - 1.0f;
    float py = 1.0f - (py_i + 0.5f) / (float)IH * 2.0f;

    const FaceG* fb = fg + b * NF;
    unsigned long long lz = ~0ull;
    unsigned int lm = 0u;

    // ---- evaluate survivors (set-bit iteration, unroll x2) ----
    while (mask) {
        int j0 = __builtin_ctzll(mask); mask &= mask - 1;
        bool have2 = mask != 0ull;
        int j1 = have2 ? __builtin_ctzll(mask) : j0;
        if (have2) mask &= mask - 1;
        int fa = base + j0, fb2 = base + j1;
        FaceG Fa = fb[fa];               // wave-uniform loads
        FaceG Fb_ = fb[fb2];
        EVALF(Fa, fa);
        if (have2) EVALF(Fb_, fb2);
    }

    int pix = b * (IH*IW) + py_i * IW + px_i;
    if (lm) atomicMax(&mkey[pix], lm);
    if (lz != ~0ull) atomicMin(&zkey[pix], lz);
}

__global__ __launch_bounds__(256) void resolve_kernel(
        const FaceG* __restrict__ fg,
        const unsigned long long* __restrict__ zkey,
        const unsigned int* __restrict__ mkey,
        const float* __restrict__ uvp,
        const float* __restrict__ tex,
        const int*  __restrict__ ft,
        float* __restrict__ imrender,
        float* __restrict__ improb)
{
#pragma clang fp contract(off)
    int pix = blockIdx.x * 256 + threadIdx.x;
    if (pix >= NPIX) return;
    int b = pix >> 14;
    int p = pix & (IH*IW - 1);
    int py_i = p >> 7;
    int px_i = p & (IW - 1);
    float px = (px_i + 0.5f) / (float)IW * 2.0f - 1.0f;
    float py = 1.0f - (py_i + 0.5f) / (float)IH * 2.0f;

    unsigned long long key = zkey[pix];
    float u = 0.0f, v = 0.0f, m = 0.0f;
    if (key != ~0ull) {
        int fidx = (int)(unsigned int)(key & 0xffffffffu);
        FaceG F = fg[b*NF + fidx];
        float w0 = (F.A.x*px + F.A.y*py) + F.A.z;
        float w1 = (F.A.w*px + F.B.x*py) + F.B.y;
        float w2 = (F.B.z*px + F.B.w*py) + F.C.x;
        float den = (w0 + w1) + w2;
        den = den + ((den >= 0.0f) ? 1e-8f : -1e-8f);
        float b0 = w0 / den, b1 = w1 / den, b2 = w2 / den;  // bit-identical to raster
        int j0 = ft[fidx*3+0], j1 = ft[fidx*3+1], j2 = ft[fidx*3+2];
        const float* ub = uvp + (size_t)b * NP * 2;
        u = (b0*ub[j0*2+0] + b1*ub[j1*2+0]) + b2*ub[j2*2+0];
        v = (b0*ub[j0*2+1] + b1*ub[j1*2+1]) + b2*ub[j2*2+1];
        m = (b0 + b1) + b2;
    }

    float gu = (u - floorf(u)) * 2.0f - 1.0f;
    float gv = (v - floorf(v)) * 2.0f - 1.0f;
    gv = -gv;
    float ix = ((gu + 1.0f) * (float)TW - 1.0f) * 0.5f;
    float iy = ((gv + 1.0f) * (float)TH - 1.0f) * 0.5f;
    float ixr = rintf(ix);   // round-half-even == jnp.round
    float iyr = rintf(iy);
    int ixn = (int)ixr, iyn = (int)iyr;
    bool tvalid = (ixn >= 0) && (ixn < TW) && (iyn >= 0) && (iyn < TH);
    int ixc = min(max(ixn, 0), TW-1);
    int iyc = min(max(iyn, 0), TH-1);
    float vmul = tvalid ? 1.0f : 0.0f;
    const float* tb = tex + (size_t)b * 3 * TH * TW;
    float tr  = tb[(0*TH + iyc)*TW + ixc] * vmul;
    float tg  = tb[(1*TH + iyc)*TW + ixc] * vmul;
    float tb2 = tb[(2*TH + iyc)*TW + ixc] * vmul;

    float o0 = fminf(fmaxf(tr  * m, 0.0f), 1.0f);
    float o1 = fminf(fmaxf(tg  * m, 0.0f), 1.0f);
    float o2 = fminf(fmaxf(tb2 * m, 0.0f), 1.0f);

    unsigned int mk = mkey[pix];
    float pr = 0.0f;
    if (mk) {
        float md = funmap(mk);
        float sxv = md / 0.02f;
        if (sxv >= 0.0f) pr = 1.0f / (1.0f + expf(-sxv));
        else { float e = expf(sxv); pr = e / (1.0f + e); }
    }

    float* outp = imrender + (size_t)pix * 3;
    outp[0] = o0; outp[1] = o1; outp[2] = o2;
    improb[pix] = pr;
}

extern "C" void kernel_launch(void* const* d_in, const int* in_sizes, int n_in,
                              void* d_out, int out_size, void* d_ws, size_t ws_size,
                              hipStream_t stream) {
    const float* points = (const float*)d_in[0];
    const int*   faces  = (const int*)  d_in[1];
    const float* rot    = (const float*)d_in[2];
    const float* cpos   = (const float*)d_in[3];
    const float* proj   = (const float*)d_in[4];
    const float* uvp    = (const float*)d_in[5];
    const float* tex    = (const float*)d_in[6];
    const int*   ft     = (const int*)  d_in[7];

    float* out        = (float*)d_out;
    float* imrender   = out;
    float* improb     = out + NB*IH*IW*3;
    float* normal_out = out + NB*IH*IW*3 + NB*IH*IW;

    char* ws = (char*)d_ws;
    FaceG*  fg   = (FaceG*) (ws + FG_OFF);
    float4* bbox = (float4*)(ws + BB_OFF);
    unsigned long long* zkey = (unsigned long long*)(ws + ZK_OFF);
    unsigned int*       mkey = (unsigned int*)      (ws + MK_OFF);

    prep_kernel<<<NPIX/256, 256, 0, stream>>>(
        points, faces, rot, cpos, proj, normal_out, fg, bbox, zkey, mkey);
    raster_kernel<<<NB*NTILE*(NSLOT/4), 256, 0, stream>>>(
        fg, bbox, zkey, mkey);
    resolve_kernel<<<(NPIX + 255)/256, 256, 0, stream>>>(
        fg, zkey, mkey, uvp, tex, ft, imrender, improb);
}

// Round 17
// 19.561 us; speedup vs baseline: 1.2916x; 1.2916x over previous
//
#include <hip/hip_runtime.h>
#include <math.h>

#define NB 2
#define NP 1200
#define NF 1000
#define IH 128
#define IW 128
#define TH 512
#define TW 512

#define TX 16
#define TY 16
#define NTILE (TX*TY)          // 256 tiles per batch
#define NPIX (NB*IH*IW)        // 32768
#define NSLOT 64               // wave-slots per tile; each owns 16 contiguous faces

// 48-byte record: [c0..c3][c4..c7][c8,z0,z1,z2]
struct __align__(16) FaceG { float4 A, B, C; };

// ws layout
#define FG_OFF   0
#define FG_BYTES (NB*NF*48)
#define BB_OFF   ((FG_BYTES + 255) & ~255)
#define BB_BYTES (NB*NF*16)
#define ZK_OFF   ((BB_OFF + BB_BYTES + 255) & ~255)
#define ZK_BYTES (NPIX*8)
#define MK_OFF   (ZK_OFF + ZK_BYTES)

// monotone float <-> uint maps (ascending order preserved)
__device__ __forceinline__ unsigned int fmap(float f) {
    unsigned int u = __float_as_uint(f);
    return (u & 0x80000000u) ? ~u : (u | 0x80000000u);
}
__device__ __forceinline__ float funmap(unsigned int u) {
    return __uint_as_float((u & 0x80000000u) ? (u & 0x7fffffffu) : ~u);
}

__global__ __launch_bounds__(256) void prep_kernel(
        const float* __restrict__ points,
        const int*  __restrict__ faces,
        const float* __restrict__ rot,
        const float* __restrict__ cpos,
        const float* __restrict__ proj,
        float* __restrict__ normal_out,
        FaceG* __restrict__ fg,
        float4* __restrict__ bbox,
        unsigned long long* __restrict__ zkey,
        unsigned int* __restrict__ mkey)
{
#pragma clang fp contract(off)
    int t = blockIdx.x * 256 + threadIdx.x;       // 0..32767
    if (t < NPIX) { zkey[t] = ~0ull; mkey[t] = 0u; }
    if (t >= NB * NF) return;
    int b = t / NF;
    int f = t - b * NF;
    const float* R = rot + b * 9;
    float ccx = cpos[b*3+0], ccy = cpos[b*3+1], ccz = cpos[b*3+2];
    float pr0 = proj[0], pr1 = proj[1], pr2 = proj[2];

    float qx[3], qy[3], qz[3], sx[3], sy[3];
    for (int k = 0; k < 3; ++k) {
        int vi = faces[f*3 + k];
        const float* P = points + (b*NP + vi) * 3;
        float vx = P[0] - ccx, vy = P[1] - ccy, vz = P[2] - ccz;
        float q0 = (vx*R[0] + vy*R[1]) + vz*R[2];
        float q1 = (vx*R[3] + vy*R[4]) + vz*R[5];
        float q2 = (vx*R[6] + vy*R[7]) + vz*R[8];
        qx[k] = q0; qy[k] = q1; qz[k] = q2;
        sx[k] = (q0*pr0) / (q2*pr2);   // IEEE divide, reference order
        sy[k] = (q1*pr1) / (q2*pr2);
    }
    float x0 = sx[0], y0 = sy[0];
    float x1 = sx[1], y1 = sy[1];
    float x2 = sx[2], y2 = sy[2];

    FaceG rec;
    rec.A = make_float4(y1 - y2, x2 - x1, x1*y2 - x2*y1, y2 - y0);
    rec.B = make_float4(x0 - x2, x2*y0 - x0*y2, y0 - y1, x1 - x0);
    rec.C = make_float4(x0*y1 - x1*y0, qz[0], qz[1], qz[2]);
    fg[t] = rec;

    float e1x = qx[1]-qx[0], e1y = qy[1]-qy[0], e1z = qz[1]-qz[0];
    float e2x = qx[2]-qx[0], e2y = qy[2]-qy[0], e2z = qz[2]-qz[0];
    float nx = e1y*e2z - e1z*e2y;
    float ny = e1z*e2x - e1x*e2z;
    float nz = e1x*e2y - e1y*e2x;
    bool front = nz > 0.0f;
    float nlen = sqrtf(((nx*nx + ny*ny) + nz*nz) + 1e-8f);
    float nd = nlen + 1e-15f;
    normal_out[t*3+0] = nx / nd;
    normal_out[t*3+1] = ny / nd;
    normal_out[t*3+2] = nz / nd;

    // conservative pixel-space bbox (xmin, ymin, xmax, ymax)
    float4 bb;
    if (!front) {
        bb = make_float4(1e9f, 1e9f, -1e9f, -1e9f);          // empty
    } else {
        float A2 = (x1-x0)*(y2-y0) - (x2-x0)*(y1-y0);
        if (fabsf(A2) < 1e-6f) {
            bb = make_float4(-1e9f, -1e9f, 1e9f, 1e9f);      // degenerate: everywhere
        } else {
            // {min bary >= -delta} == triangle scaled by (1+3*delta) about centroid;
            // delta = 0.15 -> culled faces contribute <= sigmoid(-7.5) ~ 5.5e-4.
            const float s = 1.45f;
            float cx = (x0 + x1 + x2) * (1.0f/3.0f);
            float cy = (y0 + y1 + y2) * (1.0f/3.0f);
            float xa = cx + s*(x0-cx), xb = cx + s*(x1-cx), xc = cx + s*(x2-cx);
            float ya = cy + s*(y0-cy), yb = cy + s*(y1-cy), yc = cy + s*(y2-cy);
            float xmin = fminf(fminf(xa,xb),xc), xmax = fmaxf(fmaxf(xa,xb),xc);
            float ymin = fminf(fminf(ya,yb),yc), ymax = fmaxf(fmaxf(ya,yb),yc);
            bb.x = (xmin + 1.0f) * (IW*0.5f) - 0.5f - 1.0f;  // pxmin
            bb.z = (xmax + 1.0f) * (IW*0.5f) - 0.5f + 1.0f;  // pxmax
            bb.y = (1.0f - ymax) * (IH*0.5f) - 0.5f - 1.0f;  // pymin
            bb.w = (1.0f - ymin) * (IH*0.5f) - 0.5f + 1.0f;  // pymax
        }
    }
    bbox[t] = bb;
}

#define EVALF(F_, fidx_) do {                                              \
    float w0 = ((F_).A.x*px + (F_).A.y*py) + (F_).A.z;                     \
    float w1 = ((F_).A.w*px + (F_).B.x*py) + (F_).B.y;                     \
    float w2 = ((F_).B.z*px + (F_).B.w*py) + (F_).C.x;                     \
    float den = (w0 + w1) + w2;                                            \
    den = den + ((den >= 0.0f) ? 1e-8f : -1e-8f);                          \
    bool sp = den > 0.0f;                                                  \
    float mn = fminf(fminf(w0, w1), w2);                                   \
    float mx = fmaxf(fmaxf(w0, w1), w2);                                   \
    float wsel = sp ? mn : mx;                                             \
    float dmin = wsel * __builtin_amdgcn_rcpf(den);                        \
    lm = max(lm, fmap(dmin));                                              \
    bool inside = sp ? (mn >= 0.0f) : (mx <= 0.0f);                        \
    if (inside) {                                                          \
        float b0 = w0 / den, b1 = w1 / den, b2 = w2 / den;                 \
        float z = (b0*(F_).C.y + b1*(F_).C.z) + b2*(F_).C.w;               \
        unsigned long long key =                                           \
            ((unsigned long long)fmap(z) << 32) | (unsigned int)(fidx_);   \
        lz = lz < key ? lz : key;                                          \
    }                                                                      \
} while (0)

// 8192 blocks x 4 waves = 32768 waves = 512 tiles x 64 slots.
// Wave (tile, slot) owns contiguous faces [slot*16, slot*16+16).
// Lane-parallel cull: lane i<16 tests bbox[base+i] (one coalesced round),
// ballot -> survivor mask; cold waves exit after ~1 round-trip. Small span
// keeps the hot-wave serial eval tail short (~6 survivors).
__global__ __launch_bounds__(256) void raster_kernel(
        const FaceG* __restrict__ fg,
        const float4* __restrict__ bbox,
        unsigned long long* __restrict__ zkey,
        unsigned int* __restrict__ mkey)
{
#pragma clang fp contract(off)
    unsigned int vid = (blockIdx.x * 1337u) & 8191u;   // bijective scramble
    int bt   = vid >> 4;                // 0..511 = batch*256 + tile
    int sgrp = vid & 15;                // slot group 0..15
    int b    = bt >> 8;
    int tile = bt & (NTILE - 1);
    int wib  = threadIdx.x >> 6;
    int l    = threadIdx.x & 63;
    int slot = sgrp * 4 + wib;          // 0..63
    int base = slot * 16;               // first face of this wave's span

    int tx = tile & (TX - 1), ty = tile >> 4;
    float txlo = (float)(tx << 3), txhi = (float)((tx << 3) + 7);
    float tylo = (float)(ty << 3), tyhi = (float)((ty << 3) + 7);

    // ---- lane-parallel cull: one coalesced bbox load per lane ----
    const float4* bbb = bbox + b * NF;
    int i = l & 15;
    int fi = base + i;
    bool valid = fi < NF;
    float4 bb = bbb[valid ? fi : (NF - 1)];
    bool keep = valid & (bb.x <= txhi) & (bb.z >= txlo)
                      & (bb.y <= tyhi) & (bb.w >= tylo);
    unsigned long long mask = __ballot(keep) & 0xffffull;
    if (mask == 0ull) return;           // cold wave: done after one round-trip

    int px_i = (tx << 3) | (l & 7);
    int py_i = (ty << 3) | (l >> 3);
    float px = (px_i + 0.5f) / (float)IW * 2.0f - 1.0f;
    float py = 1.0f - (py_i + 0.5f) / (float)IH * 2.0f;

    const FaceG* fb = fg + b * NF;
    unsigned long long lz = ~0ull;
    unsigned int lm = 0u;

    // ---- evaluate survivors (set-bit iteration, unroll x2) ----
    while (mask) {
        int j0 = __builtin_ctzll(mask); mask &= mask - 1;
        bool have2 = mask != 0ull;
        int j1 = have2 ? __builtin_ctzll(mask) : j0;
        if (have2) mask &= mask - 1;
        int fa = base + j0, fb2 = base + j1;
        FaceG Fa = fb[fa];               // wave-uniform loads
        FaceG Fb_ = fb[fb2];
        EVALF(Fa, fa);
        if (have2) EVALF(Fb_, fb2);
    }

    int pix = b * (IH*IW) + py_i * IW + px_i;
    if (lm) atomicMax(&mkey[pix], lm);
    if (lz != ~0ull) atomicMin(&zkey[pix], lz);
}

__global__ __launch_bounds__(256) void resolve_kernel(
        const FaceG* __restrict__ fg,
        const unsigned long long* __restrict__ zkey,
        const unsigned int* __restrict__ mkey,
        const float* __restrict__ uvp,
        const float* __restrict__ tex,
        const int*  __restrict__ ft,
        float* __restrict__ imrender,
        float* __restrict__ improb)
{
#pragma clang fp contract(off)
    int pix = blockIdx.x * 256 + threadIdx.x;
    if (pix >= NPIX) return;
    int b = pix >> 14;
    int p = pix & (IH*IW - 1);
    int py_i = p >> 7;
    int px_i = p & (IW - 1);
    float px = (px_i + 0.5f) / (float)IW * 2.0f - 1.0f;
    float py = 1.0f - (py_i + 0.5f) / (float)IH * 2.0f;

    unsigned long long key = zkey[pix];
    float u = 0.0f, v = 0.0f, m = 0.0f;
    if (key != ~0ull) {
        int fidx = (int)(unsigned int)(key & 0xffffffffu);
        FaceG F = fg[b*NF + fidx];
        float w0 = (F.A.x*px + F.A.y*py) + F.A.z;
        float w1 = (F.A.w*px + F.B.x*py) + F.B.y;
        float w2 = (F.B.z*px + F.B.w*py) + F.C.x;
        float den = (w0 + w1) + w2;
        den = den + ((den >= 0.0f) ? 1e-8f : -1e-8f);
        float b0 = w0 / den, b1 = w1 / den, b2 = w2 / den;  // bit-identical to raster
        int j0 = ft[fidx*3+0], j1 = ft[fidx*3+1], j2 = ft[fidx*3+2];
        const float* ub = uvp + (size_t)b * NP * 2;
        u = (b0*ub[j0*2+0] + b1*ub[j1*2+0]) + b2*ub[j2*2+0];
        v = (b0*ub[j0*2+1] + b1*ub[j1*2+1]) + b2*ub[j2*2+1];
        m = (b0 + b1) + b2;
    }

    float gu = (u - floorf(u)) * 2.0f - 1.0f;
    float gv = (v - floorf(v)) * 2.0f - 1.0f;
    gv = -gv;
    float ix = ((gu + 1.0f) * (float)TW - 1.0f) * 0.5f;
    float iy = ((gv + 1.0f) * (float)TH - 1.0f) * 0.5f;
    float ixr = rintf(ix);   // round-half-even == jnp.round
    float iyr = rintf(iy);
    int ixn = (int)ixr, iyn = (int)iyr;
    bool tvalid = (ixn >= 0) && (ixn < TW) && (iyn >= 0) && (iyn < TH);
    int ixc = min(max(ixn, 0), TW-1);
    int iyc = min(max(iyn, 0), TH-1);
    float vmul = tvalid ? 1.0f : 0.0f;
    const float* tb = tex + (size_t)b * 3 * TH * TW;
    float tr  = tb[(0*TH + iyc)*TW + ixc] * vmul;
    float tg  = tb[(1*TH + iyc)*TW + ixc] * vmul;
    float tb2 = tb[(2*TH + iyc)*TW + ixc] * vmul;

    float o0 = fminf(fmaxf(tr  * m, 0.0f), 1.0f);
    float o1 = fminf(fmaxf(tg  * m, 0.0f), 1.0f);
    float o2 = fminf(fmaxf(tb2 * m, 0.0f), 1.0f);

    unsigned int mk = mkey[pix];
    float pr = 0.0f;
    if (mk) {
        float md = funmap(mk);
        float sxv = md / 0.02f;
        if (sxv >= 0.0f) pr = 1.0f / (1.0f + expf(-sxv));
        else { float e = expf(sxv); pr = e / (1.0f + e); }
    }

    float* outp = imrender + (size_t)pix * 3;
    outp[0] = o0; outp[1] = o1; outp[2] = o2;
    improb[pix] = pr;
}

extern "C" void kernel_launch(void* const* d_in, const int* in_sizes, int n_in,
                              void* d_out, int out_size, void* d_ws, size_t ws_size,
                              hipStream_t stream) {
    const float* points = (const float*)d_in[0];
    const int*   faces  = (const int*)  d_in[1];
    const float* rot    = (const float*)d_in[2];
    const float* cpos   = (const float*)d_in[3];
    const float* proj   = (const float*)d_in[4];
    const float* uvp    = (const float*)d_in[5];
    const float* tex    = (const float*)d_in[6];
    const int*   ft     = (const int*)  d_in[7];

    float* out        = (float*)d_out;
    float* imrender   = out;
    float* improb     = out + NB*IH*IW*3;
    float* normal_out = out + NB*IH*IW*3 + NB*IH*IW;

    char* ws = (char*)d_ws;
    FaceG*  fg   = (FaceG*) (ws + FG_OFF);
    float4* bbox = (float4*)(ws + BB_OFF);
    unsigned long long* zkey = (unsigned long long*)(ws + ZK_OFF);
    unsigned int*       mkey = (unsigned int*)      (ws + MK_OFF);

    prep_kernel<<<NPIX/256, 256, 0, stream>>>(
        points, faces, rot, cpos, proj, normal_out, fg, bbox, zkey, mkey);
    raster_kernel<<<NB*NTILE*(NSLOT/4), 256, 0, stream>>>(
        fg, bbox, zkey, mkey);
    resolve_kernel<<<(NPIX + 255)/256, 256, 0, stream>>>(
        fg, zkey, mkey, uvp, tex, ft, imrender, improb);
}